// Round 12
// baseline (85.935 us; speedup 1.0000x reference)
//
#include <hip/hip_runtime.h>
#include <hip/hip_bf16.h>
#include <stdint.h>
#include <math.h>

#define B_SZ 4
#define T_SZ 2048
#define D_SZ 1024

constexpr int NTH = 512;

typedef short bf16x8 __attribute__((ext_vector_type(8)));
typedef float f32x4 __attribute__((ext_vector_type(4)));
typedef int i32x4 __attribute__((ext_vector_type(4)));
typedef unsigned short ushort8 __attribute__((ext_vector_type(8)));

__device__ __forceinline__ uint32_t sbf(uint32_t xu, uint32_t su) {
  return 0x3F80u | (((xu ^ su) >> 16) & 0x8000u);
}

__device__ __forceinline__ ushort f2bf(float f) {  // RNE f32->bf16
  uint32_t u = __float_as_uint(f);
  return (ushort)((u + 0x7FFFu + ((u >> 16) & 1u)) >> 16);
}

// Fragment-major layouts:
//   Qf/Kf (i8):  [b][q16=q/16][kc=k/64][q&15][k&63]
//                offset = (((b*128+q16)*16+kc)*16 + (q&15))*64 + (k&63)
//   P2  (bf16):  [b][q4=q/16][s8=s/8][q&15][s&7]
//   Vt2 (bf16):  [b][d4=d/16][s8][d&15][s&7]
// MFMA operand load: lane(l15,l4) reads 16B at frag_base + l15*64 + l4*16
// (i8) or (x4*256+s8)*128*2 + l15*16 (bf16) -> one contiguous 1KB per wave.

// ============================ PREP KERNEL =============================
// Qf,Kf: int8 sign(x)*sign(bq/bk), fragment-major.  Vt2: bf16 x*sign(bv),
// fragment-major.
__global__ __launch_bounds__(256) void prep_kernel(
    const float* __restrict__ x, const float* __restrict__ bvq,
    const float* __restrict__ bvk, const float* __restrict__ bvv,
    char* __restrict__ Qf, char* __restrict__ Kf, ushort* __restrict__ Vt2) {
  __shared__ ushort vt[64][72];
  const int bid = blockIdx.x;
  const int dt = bid & 15;
  const int tt = (bid >> 4) & 31;
  const int b = bid >> 9;
  const int t0 = tt * 64, d0 = dt * 64;
  const int tid = threadIdx.x;

#pragma unroll
  for (int p = 0; p < 4; ++p) {
    const int row = p * 16 + (tid >> 4);
    const int c4 = tid & 15;
    const size_t idx = ((size_t)(b * T_SZ + t0 + row)) * D_SZ + d0 + c4 * 4;
    float4 v = *(const float4*)(x + idx);
    float4 q = *(const float4*)(bvq + d0 + c4 * 4);
    float4 k = *(const float4*)(bvk + d0 + c4 * 4);
    float4 s = *(const float4*)(bvv + d0 + c4 * 4);
    uint32_t xu[4] = {__float_as_uint(v.x), __float_as_uint(v.y),
                      __float_as_uint(v.z), __float_as_uint(v.w)};
    uint32_t qu[4] = {__float_as_uint(q.x), __float_as_uint(q.y),
                      __float_as_uint(q.z), __float_as_uint(q.w)};
    uint32_t ku[4] = {__float_as_uint(k.x), __float_as_uint(k.y),
                      __float_as_uint(k.z), __float_as_uint(k.w)};
    uint32_t su[4] = {__float_as_uint(s.x), __float_as_uint(s.y),
                      __float_as_uint(s.z), __float_as_uint(s.w)};
    uint32_t qw = 0, kw = 0;
#pragma unroll
    for (int j = 0; j < 4; ++j) {
      uint32_t qb = ((xu[j] ^ qu[j]) & 0x80000000u) ? 0xFFu : 0x01u;
      uint32_t kb = ((xu[j] ^ ku[j]) & 0x80000000u) ? 0xFFu : 0x01u;
      qw |= qb << (8 * j);
      kw |= kb << (8 * j);
      vt[row][c4 * 4 + j] = f2bf(__uint_as_float(xu[j] ^ (su[j] & 0x80000000u)));
    }
    const int qg = t0 + row;
    const size_t fo =
        ((((size_t)(b * 128 + (qg >> 4))) * 16 + dt) * 16 + (qg & 15)) * 64 +
        c4 * 4;
    *(uint32_t*)(Qf + fo) = qw;
    *(uint32_t*)(Kf + fo) = kw;
  }
  __syncthreads();
#pragma unroll
  for (int p = 0; p < 2; ++p) {
    const int dr = p * 32 + (tid >> 3);
    const int tc = tid & 7;
    ushort8 o;
#pragma unroll
    for (int j = 0; j < 8; ++j) o[j] = vt[tc * 8 + j][dr];
    const int dglob = d0 + dr;
    const int s8 = (t0 >> 3) + tc;
    *(ushort8*)(Vt2 +
                (((size_t)(b * 64 + (dglob >> 4))) * 256 + s8) * 128 +
                (dglob & 15) * 8) = o;
  }
}

// ============================ SCORE KERNEL ============================
// Register-direct i8 GEMM (pv pattern): NO LDS, NO barriers. 128x128 tile
// per block, 8 waves (4wr x 2wc, wave 32q x 64s). Operands are contiguous
// 1KB-per-wave loads from fragment-major Qf/Kf (L2-resident, b pinned per
// XCD). Running pointers advance 1KB per kc (16 kc of 64 k).
__global__ __launch_bounds__(NTH) void score_kernel(
    const char* __restrict__ Qf, const char* __restrict__ Kf,
    ushort* __restrict__ P2) {
  const int bid = blockIdx.x;
  const int xcd = bid & 7;
  const int b = xcd >> 1;
  const int j = ((bid >> 3) << 1) + (xcd & 1);
  int qt = (int)((sqrtf(8.f * (float)j + 1.f) - 1.f) * 0.5f);
  while ((qt + 1) * (qt + 2) / 2 <= j) ++qt;
  while (qt * (qt + 1) / 2 > j) --qt;
  const int st = j - qt * (qt + 1) / 2;

  const int tid = threadIdx.x;
  const int lane = tid & 63, w = tid >> 6;
  const int wr = w >> 1, wc = w & 1;
  const int l15 = lane & 15, l4 = lane >> 4;

  i32x4 sacc[2][4];
#pragma unroll
  for (int mf = 0; mf < 2; ++mf)
#pragma unroll
    for (int nf = 0; nf < 4; ++nf) sacc[mf][nf] = (i32x4){0, 0, 0, 0};

  const int lo = l15 * 64 + l4 * 16;  // per-lane offset within 1KB fragment
  // fragment base for (x16, kc): (((b*128+x16)*16+kc)*16)*64 ; kc-stride 1KB
  const char* pQ0 = Qf + (((size_t)(b * 128 + qt * 8 + wr * 2 + 0)) << 14) + lo;
  const char* pQ1 = Qf + (((size_t)(b * 128 + qt * 8 + wr * 2 + 1)) << 14) + lo;
  const char* pK0 = Kf + (((size_t)(b * 128 + st * 8 + wc * 4 + 0)) << 14) + lo;
  const char* pK1 = Kf + (((size_t)(b * 128 + st * 8 + wc * 4 + 1)) << 14) + lo;
  const char* pK2 = Kf + (((size_t)(b * 128 + st * 8 + wc * 4 + 2)) << 14) + lo;
  const char* pK3 = Kf + (((size_t)(b * 128 + st * 8 + wc * 4 + 3)) << 14) + lo;

#pragma unroll 4
  for (int kc = 0; kc < 16; ++kc) {
    i32x4 a0 = *(const i32x4*)pQ0;
    i32x4 a1 = *(const i32x4*)pQ1;
    i32x4 b0 = *(const i32x4*)pK0;
    i32x4 b1 = *(const i32x4*)pK1;
    i32x4 b2 = *(const i32x4*)pK2;
    i32x4 b3 = *(const i32x4*)pK3;
    pQ0 += 1024; pQ1 += 1024;
    pK0 += 1024; pK1 += 1024; pK2 += 1024; pK3 += 1024;
    sacc[0][0] = __builtin_amdgcn_mfma_i32_16x16x64_i8(a0, b0, sacc[0][0], 0, 0, 0);
    sacc[0][1] = __builtin_amdgcn_mfma_i32_16x16x64_i8(a0, b1, sacc[0][1], 0, 0, 0);
    sacc[0][2] = __builtin_amdgcn_mfma_i32_16x16x64_i8(a0, b2, sacc[0][2], 0, 0, 0);
    sacc[0][3] = __builtin_amdgcn_mfma_i32_16x16x64_i8(a0, b3, sacc[0][3], 0, 0, 0);
    sacc[1][0] = __builtin_amdgcn_mfma_i32_16x16x64_i8(a1, b0, sacc[1][0], 0, 0, 0);
    sacc[1][1] = __builtin_amdgcn_mfma_i32_16x16x64_i8(a1, b1, sacc[1][1], 0, 0, 0);
    sacc[1][2] = __builtin_amdgcn_mfma_i32_16x16x64_i8(a1, b2, sacc[1][2], 0, 0, 0);
    sacc[1][3] = __builtin_amdgcn_mfma_i32_16x16x64_i8(a1, b3, sacc[1][3], 0, 0, 0);
  }

  // sigmoid + causal mask + fragment-major write (unchanged epilogue)
#pragma unroll
  for (int mf = 0; mf < 2; ++mf)
#pragma unroll
    for (int nf = 0; nf < 4; ++nf)
#pragma unroll
      for (int r = 0; r < 4; ++r) {
        const int qg = qt * 128 + wr * 32 + mf * 16 + l4 * 4 + r;
        const int sg = st * 128 + wc * 64 + nf * 16 + l15;
        float p = 1.f / (1.f + __expf(-0.125f * (float)sacc[mf][nf][r]));
        if (sg > qg) p = 0.f;
        P2[(((size_t)(b * 128 + (qg >> 4))) * 256 + (sg >> 3)) * 128 +
           (qg & 15) * 8 + (sg & 7)] = f2bf(p);
      }
}

// ============================== PV KERNEL =============================
// (R11-proven, verbatim) out = P*V, pure register GEMM, no LDS/barriers.
// Block = 64q x 128d, 4 waves. Pair (pr,31-pr): 33 s-tiles per block.
// xcd = 2b + (pr&1): all 8 ds-blocks of one (b,qt) on ONE XCD.
__global__ __launch_bounds__(256) void pv_kernel(
    const ushort* __restrict__ P2, const ushort* __restrict__ Vt2,
    float* __restrict__ out) {
  const int bid = blockIdx.x;
  const int xcd = bid & 7;
  const int idx = bid >> 3;            // 0..63
  const int ds = idx & 7;              // 128-col d-slice
  const int prh = idx >> 3;            // 0..7
  const int pr = prh * 2 + (xcd & 1);  // 0..15, parity matches xcd
  const int b = xcd >> 1;

  const int tid = threadIdx.x;
  const int lane = tid & 63, w = tid >> 6;
  const int wr = w >> 1, dg = w & 1;
  const int l15 = lane & 15, l4 = lane >> 4;

  const size_t d4base = (size_t)b * 64 + ds * 8 + dg * 4;

  for (int half = 0; half < 2; ++half) {
    const int qt = half ? (31 - pr) : pr;

    f32x4 acc[2][4];
#pragma unroll
    for (int mf = 0; mf < 2; ++mf)
#pragma unroll
      for (int nf = 0; nf < 4; ++nf) acc[mf][nf] = (f32x4){0.f, 0.f, 0.f, 0.f};

    const size_t q4base = (size_t)b * 128 + qt * 4 + wr * 2;

    const ushort* pP0 = P2 + ((q4base + 0) * 256 + l4) * 128 + l15 * 8;
    const ushort* pP1 = P2 + ((q4base + 1) * 256 + l4) * 128 + l15 * 8;
    const ushort* pV0 = Vt2 + ((d4base + 0) * 256 + l4) * 128 + l15 * 8;
    const ushort* pV1 = Vt2 + ((d4base + 1) * 256 + l4) * 128 + l15 * 8;
    const ushort* pV2 = Vt2 + ((d4base + 2) * 256 + l4) * 128 + l15 * 8;
    const ushort* pV3 = Vt2 + ((d4base + 3) * 256 + l4) * 128 + l15 * 8;

    const int nk = (qt + 1) * 2;  // k-steps of 32 s each
#pragma unroll 2
    for (int k = 0; k < nk; ++k) {
      bf16x8 pa0 = *(const bf16x8*)pP0;
      bf16x8 pa1 = *(const bf16x8*)pP1;
      bf16x8 vb0 = *(const bf16x8*)pV0;
      bf16x8 vb1 = *(const bf16x8*)pV1;
      bf16x8 vb2 = *(const bf16x8*)pV2;
      bf16x8 vb3 = *(const bf16x8*)pV3;
      pP0 += 512; pP1 += 512;
      pV0 += 512; pV1 += 512; pV2 += 512; pV3 += 512;
      acc[0][0] = __builtin_amdgcn_mfma_f32_16x16x32_bf16(pa0, vb0, acc[0][0], 0, 0, 0);
      acc[0][1] = __builtin_amdgcn_mfma_f32_16x16x32_bf16(pa0, vb1, acc[0][1], 0, 0, 0);
      acc[0][2] = __builtin_amdgcn_mfma_f32_16x16x32_bf16(pa0, vb2, acc[0][2], 0, 0, 0);
      acc[0][3] = __builtin_amdgcn_mfma_f32_16x16x32_bf16(pa0, vb3, acc[0][3], 0, 0, 0);
      acc[1][0] = __builtin_amdgcn_mfma_f32_16x16x32_bf16(pa1, vb0, acc[1][0], 0, 0, 0);
      acc[1][1] = __builtin_amdgcn_mfma_f32_16x16x32_bf16(pa1, vb1, acc[1][1], 0, 0, 0);
      acc[1][2] = __builtin_amdgcn_mfma_f32_16x16x32_bf16(pa1, vb2, acc[1][2], 0, 0, 0);
      acc[1][3] = __builtin_amdgcn_mfma_f32_16x16x32_bf16(pa1, vb3, acc[1][3], 0, 0, 0);
    }

    float* ob = out + ((size_t)(b * T_SZ + qt * 64 + wr * 32)) * D_SZ +
                ds * 128 + dg * 64;
#pragma unroll
    for (int mf = 0; mf < 2; ++mf)
#pragma unroll
      for (int nf = 0; nf < 4; ++nf)
#pragma unroll
        for (int r = 0; r < 4; ++r)
          ob[(size_t)(mf * 16 + l4 * 4 + r) * D_SZ + nf * 16 + l15] =
              acc[mf][nf][r];
  }
}

// ===================== BASE FALLBACK (no ws needed) ===================
__global__ __launch_bounds__(NTH) void hdc_attn_fallback(
    const float* __restrict__ x, const float* __restrict__ bvq,
    const float* __restrict__ bvk, const float* __restrict__ bvv,
    float* __restrict__ out) {
  __shared__ ushort Qs[32][1032];
  __shared__ ushort Ks[64][72];
  __shared__ ushort Ps[32][72];
  const int tid = threadIdx.x;
  const int lane = tid & 63;
  const int w = tid >> 6;
  const int rg = w >> 2, cg = w & 3;
  const int l15 = lane & 15, l4 = lane >> 4;
  const int b = blockIdx.x >> 6;
  const int ti = blockIdx.x & 63;
  const int t0 = ti * 32;
  {
    const float4* xr = (const float4*)(x + ((size_t)b * T_SZ + t0) * D_SZ);
    const float4* bq4 = (const float4*)bvq;
#pragma unroll
    for (int i = 0; i < 16; ++i) {
      int flat4 = tid + i * NTH;
      int row = flat4 >> 8, c4 = flat4 & 255;
      float4 v = xr[row * 256 + c4];
      float4 q = bq4[c4];
      uint32_t q0 = sbf(__float_as_uint(v.x), __float_as_uint(q.x));
      uint32_t q1 = sbf(__float_as_uint(v.y), __float_as_uint(q.y));
      uint32_t q2 = sbf(__float_as_uint(v.z), __float_as_uint(q.z));
      uint32_t q3 = sbf(__float_as_uint(v.w), __float_as_uint(q.w));
      *(uint2*)&Qs[row][c4 * 4] = make_uint2(q0 | (q1 << 16), q2 | (q3 << 16));
    }
  }
  uint32_t vsign[16];
#pragma unroll
  for (int f = 0; f < 16; ++f)
    vsign[f] = __float_as_uint(bvv[cg * 256 + f * 16 + l15]) & 0x80000000u;
  f32x4 acc[16];
#pragma unroll
  for (int f = 0; f < 16; ++f) acc[f] = (f32x4){0.f, 0.f, 0.f, 0.f};
  const int nt = (t0 + 32 + 63) / 64;
  for (int st = 0; st < nt; ++st) {
    const int s0 = st * 64;
    f32x4 sacc = (f32x4){0.f, 0.f, 0.f, 0.f};
    for (int dc = 0; dc < D_SZ / 64; ++dc) {
      __syncthreads();
      {
        const int s = tid >> 3;
        const int c8 = (tid & 7) * 8;
        const float* xk = x + ((size_t)b * T_SZ + s0 + s) * D_SZ + dc * 64 + c8;
        const float* bk = bvk + dc * 64 + c8;
        float4 v0 = *(const float4*)xk;
        float4 v1 = *(const float4*)(xk + 4);
        float4 k0 = *(const float4*)bk;
        float4 k1 = *(const float4*)(bk + 4);
        uint32_t w0 = sbf(__float_as_uint(v0.x), __float_as_uint(k0.x)) |
                      (sbf(__float_as_uint(v0.y), __float_as_uint(k0.y)) << 16);
        uint32_t w1 = sbf(__float_as_uint(v0.z), __float_as_uint(k0.z)) |
                      (sbf(__float_as_uint(v0.w), __float_as_uint(k0.w)) << 16);
        uint32_t w2 = sbf(__float_as_uint(v1.x), __float_as_uint(k1.x)) |
                      (sbf(__float_as_uint(v1.y), __float_as_uint(k1.y)) << 16);
        uint32_t w3 = sbf(__float_as_uint(v1.z), __float_as_uint(k1.z)) |
                      (sbf(__float_as_uint(v1.w), __float_as_uint(k1.w)) << 16);
        *(uint4*)&Ks[s][c8] = make_uint4(w0, w1, w2, w3);
      }
      __syncthreads();
#pragma unroll
      for (int h = 0; h < 2; ++h) {
        bf16x8 a = *(const bf16x8*)&Qs[rg * 16 + l15][dc * 64 + h * 32 + l4 * 8];
        bf16x8 kb = *(const bf16x8*)&Ks[cg * 16 + l15][h * 32 + l4 * 8];
        sacc = __builtin_amdgcn_mfma_f32_16x16x32_bf16(a, kb, sacc, 0, 0, 0);
      }
    }
    {
      const int scol = cg * 16 + l15;
      const int sg = s0 + scol;
#pragma unroll
      for (int r = 0; r < 4; ++r) {
        const int m = rg * 16 + l4 * 4 + r;
        float p = 0.f;
        if (sg <= t0 + m) p = 1.f / (1.f + __expf(-0.125f * sacc[r]));
        Ps[m][scol] = (ushort)(__float_as_uint(p) >> 16);
      }
    }
    __syncthreads();
    const float* xv = x + ((size_t)b * T_SZ + s0) * D_SZ;
#pragma unroll
    for (int kk = 0; kk < 2; ++kk) {
      bf16x8 pa = *(const bf16x8*)&Ps[rg * 16 + l15][kk * 32 + l4 * 8];
      const float* xvs = xv + (size_t)(kk * 32 + l4 * 8) * D_SZ;
#pragma unroll
      for (int f = 0; f < 16; ++f) {
        const int n = cg * 256 + f * 16 + l15;
        const float* xn = xvs + n;
        bf16x8 vb;
#pragma unroll
        for (int i = 0; i < 8; ++i) {
          uint32_t u = __float_as_uint(xn[(size_t)i * D_SZ]) ^ vsign[f];
          vb[i] = (short)(u >> 16);
        }
        acc[f] = __builtin_amdgcn_mfma_f32_16x16x32_bf16(pa, vb, acc[f], 0, 0, 0);
      }
    }
  }
  float* orow = out + ((size_t)b * T_SZ + t0) * D_SZ;
#pragma unroll
  for (int f = 0; f < 16; ++f) {
    const int n = cg * 256 + f * 16 + l15;
#pragma unroll
    for (int r = 0; r < 4; ++r) {
      const int m = rg * 16 + l4 * 4 + r;
      orow[(size_t)m * D_SZ + n] = acc[f][r];
    }
  }
}

extern "C" void kernel_launch(void* const* d_in, const int* in_sizes, int n_in,
                              void* d_out, int out_size, void* d_ws, size_t ws_size,
                              hipStream_t stream) {
  const float* x = (const float*)d_in[0];
  const float* bvq = (const float*)d_in[1];
  const float* bvk = (const float*)d_in[2];
  const float* bvv = (const float*)d_in[3];
  float* out = (float*)d_out;

  const size_t QB_SZ = (size_t)B_SZ * T_SZ * D_SZ;     // 8 MB (i8)
  const size_t VT_SZ = QB_SZ * 2;                      // 16 MB (bf16)
  const size_t P_SZ = (size_t)B_SZ * T_SZ * T_SZ * 2;  // 32 MB (bf16)
  const size_t NEED_FULL = QB_SZ * 2 + VT_SZ + P_SZ;   // 64 MB

  if (ws_size >= NEED_FULL) {
    char* Qf = (char*)d_ws;
    char* Kf = Qf + QB_SZ;
    ushort* Vt2 = (ushort*)(Kf + QB_SZ);
    ushort* P2 = (ushort*)((char*)Vt2 + VT_SZ);
    hipLaunchKernelGGL(prep_kernel, dim3(B_SZ * 32 * 16), dim3(256), 0, stream,
                       x, bvq, bvk, bvv, Qf, Kf, Vt2);
    hipLaunchKernelGGL(score_kernel, dim3(544), dim3(NTH), 0, stream,
                       Qf, Kf, P2);
    hipLaunchKernelGGL(pv_kernel, dim3(512), dim3(256), 0, stream,
                       P2, Vt2, out);
  } else {
    hipLaunchKernelGGL(hdc_attn_fallback, dim3(B_SZ * 64), dim3(NTH), 0, stream,
                       x, bvq, bvk, bvv, out);
  }
}

// Round 13
// 78.572 us; speedup vs baseline: 1.0937x; 1.0937x over previous
//
#include <hip/hip_runtime.h>
#include <hip/hip_bf16.h>
#include <stdint.h>
#include <math.h>

#define B_SZ 4
#define T_SZ 2048
#define D_SZ 1024

constexpr int NTH = 512;

typedef short bf16x8 __attribute__((ext_vector_type(8)));
typedef float f32x4 __attribute__((ext_vector_type(4)));
typedef int i32x4 __attribute__((ext_vector_type(4)));
typedef unsigned short ushort8 __attribute__((ext_vector_type(8)));

__device__ __forceinline__ uint32_t sbf(uint32_t xu, uint32_t su) {
  return 0x3F80u | (((xu ^ su) >> 16) & 0x8000u);
}

__device__ __forceinline__ ushort f2bf(float f) {  // RNE f32->bf16
  uint32_t u = __float_as_uint(f);
  return (ushort)((u + 0x7FFFu + ((u >> 16) & 1u)) >> 16);
}

// async 16B global->LDS (dest = wave-uniform base + lane*16 pattern)
__device__ __forceinline__ void glds16(const void* g, void* l) {
  __builtin_amdgcn_global_load_lds(
      (const __attribute__((address_space(1))) void*)g,
      (__attribute__((address_space(3))) void*)l, 16, 0, 0);
}

// Fragment-major layouts (bf16):
//   P2[b][q4=q/16][s8=s/8][q&15][s&7]   : q4-stride 256*128, s8-stride 128
//   Vt2[b][d4=d/16][s8][d&15][s&7]
// MFMA operand load: lane(l15,l4) reads 16B -> one contiguous 1KB per wave.

// ============================ PREP KERNEL =============================
// (R11-proven, verbatim) Qb,Kb: int8 signs in [B][T][D].  Vt2: bf16
// x*sign(bv), fragment-major.
__global__ __launch_bounds__(256) void prep_kernel(
    const float* __restrict__ x, const float* __restrict__ bvq,
    const float* __restrict__ bvk, const float* __restrict__ bvv,
    char* __restrict__ Qb, char* __restrict__ Kb, ushort* __restrict__ Vt2) {
  __shared__ ushort vt[64][72];
  const int bid = blockIdx.x;
  const int dt = bid & 15;
  const int tt = (bid >> 4) & 31;
  const int b = bid >> 9;
  const int t0 = tt * 64, d0 = dt * 64;
  const int tid = threadIdx.x;

#pragma unroll
  for (int p = 0; p < 4; ++p) {
    const int row = p * 16 + (tid >> 4);
    const int c4 = tid & 15;
    const size_t idx = ((size_t)(b * T_SZ + t0 + row)) * D_SZ + d0 + c4 * 4;
    float4 v = *(const float4*)(x + idx);
    float4 q = *(const float4*)(bvq + d0 + c4 * 4);
    float4 k = *(const float4*)(bvk + d0 + c4 * 4);
    float4 s = *(const float4*)(bvv + d0 + c4 * 4);
    uint32_t xu[4] = {__float_as_uint(v.x), __float_as_uint(v.y),
                      __float_as_uint(v.z), __float_as_uint(v.w)};
    uint32_t qu[4] = {__float_as_uint(q.x), __float_as_uint(q.y),
                      __float_as_uint(q.z), __float_as_uint(q.w)};
    uint32_t ku[4] = {__float_as_uint(k.x), __float_as_uint(k.y),
                      __float_as_uint(k.z), __float_as_uint(k.w)};
    uint32_t su[4] = {__float_as_uint(s.x), __float_as_uint(s.y),
                      __float_as_uint(s.z), __float_as_uint(s.w)};
    uint32_t qw = 0, kw = 0;
#pragma unroll
    for (int j = 0; j < 4; ++j) {
      uint32_t qb = ((xu[j] ^ qu[j]) & 0x80000000u) ? 0xFFu : 0x01u;
      uint32_t kb = ((xu[j] ^ ku[j]) & 0x80000000u) ? 0xFFu : 0x01u;
      qw |= qb << (8 * j);
      kw |= kb << (8 * j);
      vt[row][c4 * 4 + j] = f2bf(__uint_as_float(xu[j] ^ (su[j] & 0x80000000u)));
    }
    *(uint32_t*)(Qb + idx) = qw;
    *(uint32_t*)(Kb + idx) = kw;
  }
  __syncthreads();
#pragma unroll
  for (int p = 0; p < 2; ++p) {
    const int dr = p * 32 + (tid >> 3);
    const int tc = tid & 7;
    ushort8 o;
#pragma unroll
    for (int j = 0; j < 8; ++j) o[j] = vt[tc * 8 + j][dr];
    const int dglob = d0 + dr;
    const int s8 = (t0 >> 3) + tc;
    *(ushort8*)(Vt2 +
                (((size_t)(b * 64 + (dglob >> 4))) * 256 + s8) * 128 +
                (dglob & 15) * 8) = o;
  }
}

// ============================ SCORE KERNEL ============================
// (R11-proven, verbatim) 128x128 tile per block, 8 waves (wave = 32q x 64s),
// BK=128, LDS double-buffered; order: vmcnt(0) -> barrier -> STAGE(next).
// Final store goes to fragment-major P2.
__global__ __launch_bounds__(NTH) void score_kernel(
    const char* __restrict__ Qb, const char* __restrict__ Kb,
    ushort* __restrict__ P2) {
  __shared__ __align__(16) unsigned char Qs[2][128 * 128];  // 32 KB
  __shared__ __align__(16) unsigned char Ks[2][128 * 128];  // 32 KB

  const int bid = blockIdx.x;
  const int xcd = bid & 7;
  const int b = xcd >> 1;
  const int j = ((bid >> 3) << 1) + (xcd & 1);
  int qt = (int)((sqrtf(8.f * (float)j + 1.f) - 1.f) * 0.5f);
  while ((qt + 1) * (qt + 2) / 2 <= j) ++qt;
  while (qt * (qt + 1) / 2 > j) --qt;
  const int st = j - qt * (qt + 1) / 2;

  const int tid = threadIdx.x;
  const int lane = tid & 63, w = tid >> 6;
  const int wr = w >> 1, wc = w & 1;
  const int l15 = lane & 15, l4 = lane >> 4;

  const size_t qrow0 = ((size_t)(b * T_SZ + qt * 128)) * D_SZ;
  const size_t krow0 = ((size_t)(b * T_SZ + st * 128)) * D_SZ;

  i32x4 sacc[2][4];
#pragma unroll
  for (int mf = 0; mf < 2; ++mf)
#pragma unroll
    for (int nf = 0; nf < 4; ++nf) sacc[mf][nf] = (i32x4){0, 0, 0, 0};

  auto STAGE = [&](int buf, int ks) {
#pragma unroll
    for (int i = 0; i < 4; ++i) {
      const int isK = i >> 1;
      const int fi = tid + (i & 1) * 512;
      const int row = fi >> 3, c = fi & 7;
      const int cs = c ^ (row & 7);
      const char* src = (isK ? Kb + krow0 : Qb + qrow0) +
                        (size_t)row * D_SZ + ks * 128 + cs * 16;
      unsigned char* dst = (isK ? Ks[buf] : Qs[buf]) + fi * 16;
      glds16(src, dst);
    }
  };

  STAGE(0, 0);
  for (int ks = 0; ks < 8; ++ks) {
    asm volatile("s_waitcnt vmcnt(0)" ::: "memory");
    __builtin_amdgcn_s_barrier();
    if (ks + 1 < 8) STAGE((ks + 1) & 1, ks + 1);
    const int buf = ks & 1;
#pragma unroll
    for (int kc = 0; kc < 2; ++kc) {
      i32x4 af[2], bfr[4];
#pragma unroll
      for (int mf = 0; mf < 2; ++mf) {
        const int row = wr * 32 + mf * 16 + l15;
        const int ch = (kc * 4 + l4) ^ (row & 7);
        af[mf] = *(const i32x4*)(Qs[buf] + row * 128 + ch * 16);
      }
#pragma unroll
      for (int nf = 0; nf < 4; ++nf) {
        const int row = wc * 64 + nf * 16 + l15;
        const int ch = (kc * 4 + l4) ^ (row & 7);
        bfr[nf] = *(const i32x4*)(Ks[buf] + row * 128 + ch * 16);
      }
#pragma unroll
      for (int mf = 0; mf < 2; ++mf)
#pragma unroll
        for (int nf = 0; nf < 4; ++nf)
          sacc[mf][nf] = __builtin_amdgcn_mfma_i32_16x16x64_i8(
              af[mf], bfr[nf], sacc[mf][nf], 0, 0, 0);
    }
    asm volatile("s_waitcnt lgkmcnt(0)" ::: "memory");
  }

  // sigmoid + causal mask + fragment-major write
#pragma unroll
  for (int mf = 0; mf < 2; ++mf)
#pragma unroll
    for (int nf = 0; nf < 4; ++nf)
#pragma unroll
      for (int r = 0; r < 4; ++r) {
        const int qg = qt * 128 + wr * 32 + mf * 16 + l4 * 4 + r;
        const int sg = st * 128 + wc * 64 + nf * 16 + l15;
        float p = 1.f / (1.f + __expf(-0.125f * (float)sacc[mf][nf][r]));
        if (sg > qg) p = 0.f;
        P2[(((size_t)(b * 128 + (qg >> 4))) * 256 + (sg >> 3)) * 128 +
           (qg & 15) * 8 + (sg & 7)] = f2bf(p);
      }
}

// ============================== PV KERNEL =============================
// out = P*V, pure register GEMM, no LDS/barriers. Wave = 64q x 64d:
// 4 P-frags x 4 V-frags -> 16 MFMAs per 8 KB loaded (2x reuse vs R11).
// Block = 4 waves (2x2) = 128q x 128d q-tile qt (0..15), nk = 4*qt+4
// k-steps of 32 s. Grid 512 (2 blk/CU), big-qt-first. XCD map
// xcd = 2b + (qt&1): all 8 ds-blocks of one (b,qt) P-panel (512 KB) on one
// XCD; V[b] (4 MB) L2-resident.
__global__ __launch_bounds__(256) void pv_kernel(
    const ushort* __restrict__ P2, const ushort* __restrict__ Vt2,
    float* __restrict__ out) {
  const int bid = blockIdx.x;
  const int xcd = bid & 7;
  const int b = xcd >> 1;
  const int par = xcd & 1;
  const int t = bid >> 3;          // 0..63
  const int ds = t & 7;            // 128-col d-slice
  const int qi = 7 - (t >> 3);     // big-first
  const int qt = qi * 2 + par;     // 0..15 (128-row q-tile)

  const int tid = threadIdx.x;
  const int lane = tid & 63, w = tid >> 6;
  const int wr = w >> 1, dg = w & 1;
  const int l15 = lane & 15, l4 = lane >> 4;

  f32x4 acc[4][4];
#pragma unroll
  for (int mf = 0; mf < 4; ++mf)
#pragma unroll
    for (int nf = 0; nf < 4; ++nf) acc[mf][nf] = (f32x4){0.f, 0.f, 0.f, 0.f};

  const size_t q4base = (size_t)b * 128 + qt * 8 + wr * 4;
  const size_t d4base = (size_t)b * 64 + ds * 8 + dg * 4;

  const ushort* pP[4];
  const ushort* pV[4];
#pragma unroll
  for (int i = 0; i < 4; ++i) {
    pP[i] = P2 + ((q4base + i) * 256 + l4) * 128 + l15 * 8;
    pV[i] = Vt2 + ((d4base + i) * 256 + l4) * 128 + l15 * 8;
  }

  const int nk = qt * 4 + 4;  // k-steps of 32 s
#pragma unroll 2
  for (int k = 0; k < nk; ++k) {
    bf16x8 pa[4], vb[4];
#pragma unroll
    for (int i = 0; i < 4; ++i) {
      pa[i] = *(const bf16x8*)pP[i];
      vb[i] = *(const bf16x8*)pV[i];
    }
#pragma unroll
    for (int i = 0; i < 4; ++i) {
      pP[i] += 512;
      pV[i] += 512;
    }
#pragma unroll
    for (int mf = 0; mf < 4; ++mf)
#pragma unroll
      for (int nf = 0; nf < 4; ++nf)
        acc[mf][nf] = __builtin_amdgcn_mfma_f32_16x16x32_bf16(
            pa[mf], vb[nf], acc[mf][nf], 0, 0, 0);
  }

  float* ob = out + ((size_t)(b * T_SZ + qt * 128 + wr * 64)) * D_SZ +
              ds * 128 + dg * 64;
#pragma unroll
  for (int mf = 0; mf < 4; ++mf)
#pragma unroll
    for (int nf = 0; nf < 4; ++nf)
#pragma unroll
      for (int r = 0; r < 4; ++r)
        ob[(size_t)(mf * 16 + l4 * 4 + r) * D_SZ + nf * 16 + l15] =
            acc[mf][nf][r];
}

// ===================== BASE FALLBACK (no ws needed) ===================
__global__ __launch_bounds__(NTH) void hdc_attn_fallback(
    const float* __restrict__ x, const float* __restrict__ bvq,
    const float* __restrict__ bvk, const float* __restrict__ bvv,
    float* __restrict__ out) {
  __shared__ ushort Qs[32][1032];
  __shared__ ushort Ks[64][72];
  __shared__ ushort Ps[32][72];
  const int tid = threadIdx.x;
  const int lane = tid & 63;
  const int w = tid >> 6;
  const int rg = w >> 2, cg = w & 3;
  const int l15 = lane & 15, l4 = lane >> 4;
  const int b = blockIdx.x >> 6;
  const int ti = blockIdx.x & 63;
  const int t0 = ti * 32;
  {
    const float4* xr = (const float4*)(x + ((size_t)b * T_SZ + t0) * D_SZ);
    const float4* bq4 = (const float4*)bvq;
#pragma unroll
    for (int i = 0; i < 16; ++i) {
      int flat4 = tid + i * NTH;
      int row = flat4 >> 8, c4 = flat4 & 255;
      float4 v = xr[row * 256 + c4];
      float4 q = bq4[c4];
      uint32_t q0 = sbf(__float_as_uint(v.x), __float_as_uint(q.x));
      uint32_t q1 = sbf(__float_as_uint(v.y), __float_as_uint(q.y));
      uint32_t q2 = sbf(__float_as_uint(v.z), __float_as_uint(q.z));
      uint32_t q3 = sbf(__float_as_uint(v.w), __float_as_uint(q.w));
      *(uint2*)&Qs[row][c4 * 4] = make_uint2(q0 | (q1 << 16), q2 | (q3 << 16));
    }
  }
  uint32_t vsign[16];
#pragma unroll
  for (int f = 0; f < 16; ++f)
    vsign[f] = __float_as_uint(bvv[cg * 256 + f * 16 + l15]) & 0x80000000u;
  f32x4 acc[16];
#pragma unroll
  for (int f = 0; f < 16; ++f) acc[f] = (f32x4){0.f, 0.f, 0.f, 0.f};
  const int nt = (t0 + 32 + 63) / 64;
  for (int st = 0; st < nt; ++st) {
    const int s0 = st * 64;
    f32x4 sacc = (f32x4){0.f, 0.f, 0.f, 0.f};
    for (int dc = 0; dc < D_SZ / 64; ++dc) {
      __syncthreads();
      {
        const int s = tid >> 3;
        const int c8 = (tid & 7) * 8;
        const float* xk = x + ((size_t)b * T_SZ + s0 + s) * D_SZ + dc * 64 + c8;
        const float* bk = bvk + dc * 64 + c8;
        float4 v0 = *(const float4*)xk;
        float4 v1 = *(const float4*)(xk + 4);
        float4 k0 = *(const float4*)bk;
        float4 k1 = *(const float4*)(bk + 4);
        uint32_t w0 = sbf(__float_as_uint(v0.x), __float_as_uint(k0.x)) |
                      (sbf(__float_as_uint(v0.y), __float_as_uint(k0.y)) << 16);
        uint32_t w1 = sbf(__float_as_uint(v0.z), __float_as_uint(k0.z)) |
                      (sbf(__float_as_uint(v0.w), __float_as_uint(k0.w)) << 16);
        uint32_t w2 = sbf(__float_as_uint(v1.x), __float_as_uint(k1.x)) |
                      (sbf(__float_as_uint(v1.y), __float_as_uint(k1.y)) << 16);
        uint32_t w3 = sbf(__float_as_uint(v1.z), __float_as_uint(k1.z)) |
                      (sbf(__float_as_uint(v1.w), __float_as_uint(k1.w)) << 16);
        *(uint4*)&Ks[s][c8] = make_uint4(w0, w1, w2, w3);
      }
      __syncthreads();
#pragma unroll
      for (int h = 0; h < 2; ++h) {
        bf16x8 a = *(const bf16x8*)&Qs[rg * 16 + l15][dc * 64 + h * 32 + l4 * 8];
        bf16x8 kb = *(const bf16x8*)&Ks[cg * 16 + l15][h * 32 + l4 * 8];
        sacc = __builtin_amdgcn_mfma_f32_16x16x32_bf16(a, kb, sacc, 0, 0, 0);
      }
    }
    {
      const int scol = cg * 16 + l15;
      const int sg = s0 + scol;
#pragma unroll
      for (int r = 0; r < 4; ++r) {
        const int m = rg * 16 + l4 * 4 + r;
        float p = 0.f;
        if (sg <= t0 + m) p = 1.f / (1.f + __expf(-0.125f * sacc[r]));
        Ps[m][scol] = (ushort)(__float_as_uint(p) >> 16);
      }
    }
    __syncthreads();
    const float* xv = x + ((size_t)b * T_SZ + s0) * D_SZ;
#pragma unroll
    for (int kk = 0; kk < 2; ++kk) {
      bf16x8 pa = *(const bf16x8*)&Ps[rg * 16 + l15][kk * 32 + l4 * 8];
      const float* xvs = xv + (size_t)(kk * 32 + l4 * 8) * D_SZ;
#pragma unroll
      for (int f = 0; f < 16; ++f) {
        const int n = cg * 256 + f * 16 + l15;
        const float* xn = xvs + n;
        bf16x8 vb;
#pragma unroll
        for (int i = 0; i < 8; ++i) {
          uint32_t u = __float_as_uint(xn[(size_t)i * D_SZ]) ^ vsign[f];
          vb[i] = (short)(u >> 16);
        }
        acc[f] = __builtin_amdgcn_mfma_f32_16x16x32_bf16(pa, vb, acc[f], 0, 0, 0);
      }
    }
  }
  float* orow = out + ((size_t)b * T_SZ + t0) * D_SZ;
#pragma unroll
  for (int f = 0; f < 16; ++f) {
    const int n = cg * 256 + f * 16 + l15;
#pragma unroll
    for (int r = 0; r < 4; ++r) {
      const int m = rg * 16 + l4 * 4 + r;
      orow[(size_t)m * D_SZ + n] = acc[f][r];
    }
  }
}

extern "C" void kernel_launch(void* const* d_in, const int* in_sizes, int n_in,
                              void* d_out, int out_size, void* d_ws, size_t ws_size,
                              hipStream_t stream) {
  const float* x = (const float*)d_in[0];
  const float* bvq = (const float*)d_in[1];
  const float* bvk = (const float*)d_in[2];
  const float* bvv = (const float*)d_in[3];
  float* out = (float*)d_out;

  const size_t QB_SZ = (size_t)B_SZ * T_SZ * D_SZ;     // 8 MB (i8)
  const size_t VT_SZ = QB_SZ * 2;                      // 16 MB (bf16)
  const size_t P_SZ = (size_t)B_SZ * T_SZ * T_SZ * 2;  // 32 MB (bf16)
  const size_t NEED_FULL = QB_SZ * 2 + VT_SZ + P_SZ;   // 64 MB

  if (ws_size >= NEED_FULL) {
    char* Qb = (char*)d_ws;
    char* Kb = Qb + QB_SZ;
    ushort* Vt2 = (ushort*)(Kb + QB_SZ);
    ushort* P2 = (ushort*)((char*)Vt2 + VT_SZ);
    hipLaunchKernelGGL(prep_kernel, dim3(B_SZ * 32 * 16), dim3(256), 0, stream,
                       x, bvq, bvk, bvv, Qb, Kb, Vt2);
    hipLaunchKernelGGL(score_kernel, dim3(544), dim3(NTH), 0, stream,
                       Qb, Kb, P2);
    hipLaunchKernelGGL(pv_kernel, dim3(512), dim3(256), 0, stream,
                       P2, Vt2, out);
  } else {
    hipLaunchKernelGGL(hdc_attn_fallback, dim3(B_SZ * 64), dim3(NTH), 0, stream,
                       x, bvq, bvk, bvv, out);
  }
}

// Round 14
// 72.026 us; speedup vs baseline: 1.1931x; 1.0909x over previous
//
#include <hip/hip_runtime.h>
#include <hip/hip_bf16.h>
#include <stdint.h>
#include <math.h>

#define B_SZ 4
#define T_SZ 2048
#define D_SZ 1024

constexpr int NTH = 512;

typedef short bf16x8 __attribute__((ext_vector_type(8)));
typedef float f32x4 __attribute__((ext_vector_type(4)));
typedef int i32x4 __attribute__((ext_vector_type(4)));
typedef unsigned short ushort8 __attribute__((ext_vector_type(8)));

__device__ __forceinline__ uint32_t sbf(uint32_t xu, uint32_t su) {
  return 0x3F80u | (((xu ^ su) >> 16) & 0x8000u);
}

__device__ __forceinline__ ushort f2bf(float f) {  // RNE f32->bf16
  uint32_t u = __float_as_uint(f);
  return (ushort)((u + 0x7FFFu + ((u >> 16) & 1u)) >> 16);
}

// async 16B global->LDS (dest = wave-uniform base + lane*16 pattern)
__device__ __forceinline__ void glds16(const void* g, void* l) {
  __builtin_amdgcn_global_load_lds(
      (const __attribute__((address_space(1))) void*)g,
      (__attribute__((address_space(3))) void*)l, 16, 0, 0);
}

// Fragment-major layouts (bf16):
//   P2[b][q4=q/16][s8=s/8][q&15][s&7]   : q4-stride 256*128, s8-stride 128
//   Vt2[b][d4=d/16][s8][d&15][s&7]
// MFMA operand load: lane(l15,l4) reads 16B -> one contiguous 1KB per wave.

// ============================ PREP KERNEL =============================
// (R11-proven, verbatim) Qb,Kb: int8 signs in [B][T][D].  Vt2: bf16
// x*sign(bv), fragment-major.
__global__ __launch_bounds__(256) void prep_kernel(
    const float* __restrict__ x, const float* __restrict__ bvq,
    const float* __restrict__ bvk, const float* __restrict__ bvv,
    char* __restrict__ Qb, char* __restrict__ Kb, ushort* __restrict__ Vt2) {
  __shared__ ushort vt[64][72];
  const int bid = blockIdx.x;
  const int dt = bid & 15;
  const int tt = (bid >> 4) & 31;
  const int b = bid >> 9;
  const int t0 = tt * 64, d0 = dt * 64;
  const int tid = threadIdx.x;

#pragma unroll
  for (int p = 0; p < 4; ++p) {
    const int row = p * 16 + (tid >> 4);
    const int c4 = tid & 15;
    const size_t idx = ((size_t)(b * T_SZ + t0 + row)) * D_SZ + d0 + c4 * 4;
    float4 v = *(const float4*)(x + idx);
    float4 q = *(const float4*)(bvq + d0 + c4 * 4);
    float4 k = *(const float4*)(bvk + d0 + c4 * 4);
    float4 s = *(const float4*)(bvv + d0 + c4 * 4);
    uint32_t xu[4] = {__float_as_uint(v.x), __float_as_uint(v.y),
                      __float_as_uint(v.z), __float_as_uint(v.w)};
    uint32_t qu[4] = {__float_as_uint(q.x), __float_as_uint(q.y),
                      __float_as_uint(q.z), __float_as_uint(q.w)};
    uint32_t ku[4] = {__float_as_uint(k.x), __float_as_uint(k.y),
                      __float_as_uint(k.z), __float_as_uint(k.w)};
    uint32_t su[4] = {__float_as_uint(s.x), __float_as_uint(s.y),
                      __float_as_uint(s.z), __float_as_uint(s.w)};
    uint32_t qw = 0, kw = 0;
#pragma unroll
    for (int j = 0; j < 4; ++j) {
      uint32_t qb = ((xu[j] ^ qu[j]) & 0x80000000u) ? 0xFFu : 0x01u;
      uint32_t kb = ((xu[j] ^ ku[j]) & 0x80000000u) ? 0xFFu : 0x01u;
      qw |= qb << (8 * j);
      kw |= kb << (8 * j);
      vt[row][c4 * 4 + j] = f2bf(__uint_as_float(xu[j] ^ (su[j] & 0x80000000u)));
    }
    *(uint32_t*)(Qb + idx) = qw;
    *(uint32_t*)(Kb + idx) = kw;
  }
  __syncthreads();
#pragma unroll
  for (int p = 0; p < 2; ++p) {
    const int dr = p * 32 + (tid >> 3);
    const int tc = tid & 7;
    ushort8 o;
#pragma unroll
    for (int j = 0; j < 8; ++j) o[j] = vt[tc * 8 + j][dr];
    const int dglob = d0 + dr;
    const int s8 = (t0 >> 3) + tc;
    *(ushort8*)(Vt2 +
                (((size_t)(b * 64 + (dglob >> 4))) * 256 + s8) * 128 +
                (dglob & 15) * 8) = o;
  }
}

// ============================ SCORE KERNEL ============================
// 128x128 tile per block, 8 waves (wave = 32q x 64s). BK=64, TRIPLE-buffered
// (48 KB -> 3 blk/CU), distance-2 prefetch, counted vmcnt(2) mid-loop.
// Invariant (R7 lesson): each wave waits its OWN tile-t loads BEFORE the
// barrier; after the barrier the whole tile is staged. 64B rows -> b128
// reads minimally banked, no swizzle. Epilogue -> fragment-major P2.
__global__ __launch_bounds__(NTH) void score_kernel(
    const char* __restrict__ Qb, const char* __restrict__ Kb,
    ushort* __restrict__ P2) {
  __shared__ __align__(16) unsigned char Qs[3][128 * 64];  // 24 KB
  __shared__ __align__(16) unsigned char Ks[3][128 * 64];  // 24 KB

  const int bid = blockIdx.x;
  const int xcd = bid & 7;
  const int b = xcd >> 1;
  const int j = ((bid >> 3) << 1) + (xcd & 1);
  int qt = (int)((sqrtf(8.f * (float)j + 1.f) - 1.f) * 0.5f);
  while ((qt + 1) * (qt + 2) / 2 <= j) ++qt;
  while (qt * (qt + 1) / 2 > j) --qt;
  const int st = j - qt * (qt + 1) / 2;

  const int tid = threadIdx.x;
  const int lane = tid & 63, w = tid >> 6;
  const int wr = w >> 1, wc = w & 1;
  const int l15 = lane & 15, l4 = lane >> 4;

  const size_t qrow0 = ((size_t)(b * T_SZ + qt * 128)) * D_SZ;
  const size_t krow0 = ((size_t)(b * T_SZ + st * 128)) * D_SZ;

  i32x4 sacc[2][4];
#pragma unroll
  for (int mf = 0; mf < 2; ++mf)
#pragma unroll
    for (int nf = 0; nf < 4; ++nf) sacc[mf][nf] = (i32x4){0, 0, 0, 0};

  // stage 64-k chunk ks: 1 Q chunk + 1 K chunk per thread (512 x 16B each)
  const int srow = tid >> 2, sc = (tid & 3) * 16;  // row 0..127, 16B chunk
  auto STAGE = [&](int buf, int ks) {
    glds16(Qb + qrow0 + (size_t)srow * D_SZ + ks * 64 + sc,
           Qs[buf] + tid * 16);
    glds16(Kb + krow0 + (size_t)srow * D_SZ + ks * 64 + sc,
           Ks[buf] + tid * 16);
  };

  STAGE(0, 0);
  STAGE(1, 1);
  for (int t = 0; t < 16; ++t) {
    if (t < 15)
      asm volatile("s_waitcnt vmcnt(2)" ::: "memory");  // own tile-t loads done
    else
      asm volatile("s_waitcnt vmcnt(0)" ::: "memory");
    __builtin_amdgcn_s_barrier();                       // whole tile staged
    if (t + 2 < 16) STAGE((t + 2) % 3, t + 2);          // prefetch t+2
    const int buf = t % 3;
    i32x4 af[2], bfr[4];
#pragma unroll
    for (int mf = 0; mf < 2; ++mf) {
      const int row = wr * 32 + mf * 16 + l15;
      af[mf] = *(const i32x4*)(Qs[buf] + row * 64 + l4 * 16);
    }
#pragma unroll
    for (int nf = 0; nf < 4; ++nf) {
      const int row = wc * 64 + nf * 16 + l15;
      bfr[nf] = *(const i32x4*)(Ks[buf] + row * 64 + l4 * 16);
    }
#pragma unroll
    for (int mf = 0; mf < 2; ++mf)
#pragma unroll
      for (int nf = 0; nf < 4; ++nf)
        sacc[mf][nf] = __builtin_amdgcn_mfma_i32_16x16x64_i8(
            af[mf], bfr[nf], sacc[mf][nf], 0, 0, 0);
    asm volatile("s_waitcnt lgkmcnt(0)" ::: "memory");  // LDS reads drained
  }

  // sigmoid + causal mask + fragment-major write
#pragma unroll
  for (int mf = 0; mf < 2; ++mf)
#pragma unroll
    for (int nf = 0; nf < 4; ++nf)
#pragma unroll
      for (int r = 0; r < 4; ++r) {
        const int qg = qt * 128 + wr * 32 + mf * 16 + l4 * 4 + r;
        const int sg = st * 128 + wc * 64 + nf * 16 + l15;
        float p = 1.f / (1.f + __expf(-0.125f * (float)sacc[mf][nf][r]));
        if (sg > qg) p = 0.f;
        P2[(((size_t)(b * 128 + (qg >> 4))) * 256 + (sg >> 3)) * 128 +
           (qg & 15) * 8 + (sg & 7)] = f2bf(p);
      }
}

// ============================== PV KERNEL =============================
// (R11-proven, verbatim) out = P*V, pure register GEMM, no LDS/barriers.
// Block = 64q x 128d, 4 waves. Pair (pr,31-pr): 33 s-tiles per block.
// xcd = 2b + (pr&1): all 8 ds-blocks of one (b,qt) on ONE XCD.
__global__ __launch_bounds__(256) void pv_kernel(
    const ushort* __restrict__ P2, const ushort* __restrict__ Vt2,
    float* __restrict__ out) {
  const int bid = blockIdx.x;
  const int xcd = bid & 7;
  const int idx = bid >> 3;            // 0..63
  const int ds = idx & 7;              // 128-col d-slice
  const int prh = idx >> 3;            // 0..7
  const int pr = prh * 2 + (xcd & 1);  // 0..15, parity matches xcd
  const int b = xcd >> 1;

  const int tid = threadIdx.x;
  const int lane = tid & 63, w = tid >> 6;
  const int wr = w >> 1, dg = w & 1;
  const int l15 = lane & 15, l4 = lane >> 4;

  const size_t d4base = (size_t)b * 64 + ds * 8 + dg * 4;

  for (int half = 0; half < 2; ++half) {
    const int qt = half ? (31 - pr) : pr;

    f32x4 acc[2][4];
#pragma unroll
    for (int mf = 0; mf < 2; ++mf)
#pragma unroll
      for (int nf = 0; nf < 4; ++nf) acc[mf][nf] = (f32x4){0.f, 0.f, 0.f, 0.f};

    const size_t q4base = (size_t)b * 128 + qt * 4 + wr * 2;

    const ushort* pP0 = P2 + ((q4base + 0) * 256 + l4) * 128 + l15 * 8;
    const ushort* pP1 = P2 + ((q4base + 1) * 256 + l4) * 128 + l15 * 8;
    const ushort* pV0 = Vt2 + ((d4base + 0) * 256 + l4) * 128 + l15 * 8;
    const ushort* pV1 = Vt2 + ((d4base + 1) * 256 + l4) * 128 + l15 * 8;
    const ushort* pV2 = Vt2 + ((d4base + 2) * 256 + l4) * 128 + l15 * 8;
    const ushort* pV3 = Vt2 + ((d4base + 3) * 256 + l4) * 128 + l15 * 8;

    const int nk = (qt + 1) * 2;  // k-steps of 32 s each
#pragma unroll 2
    for (int k = 0; k < nk; ++k) {
      bf16x8 pa0 = *(const bf16x8*)pP0;
      bf16x8 pa1 = *(const bf16x8*)pP1;
      bf16x8 vb0 = *(const bf16x8*)pV0;
      bf16x8 vb1 = *(const bf16x8*)pV1;
      bf16x8 vb2 = *(const bf16x8*)pV2;
      bf16x8 vb3 = *(const bf16x8*)pV3;
      pP0 += 512; pP1 += 512;
      pV0 += 512; pV1 += 512; pV2 += 512; pV3 += 512;
      acc[0][0] = __builtin_amdgcn_mfma_f32_16x16x32_bf16(pa0, vb0, acc[0][0], 0, 0, 0);
      acc[0][1] = __builtin_amdgcn_mfma_f32_16x16x32_bf16(pa0, vb1, acc[0][1], 0, 0, 0);
      acc[0][2] = __builtin_amdgcn_mfma_f32_16x16x32_bf16(pa0, vb2, acc[0][2], 0, 0, 0);
      acc[0][3] = __builtin_amdgcn_mfma_f32_16x16x32_bf16(pa0, vb3, acc[0][3], 0, 0, 0);
      acc[1][0] = __builtin_amdgcn_mfma_f32_16x16x32_bf16(pa1, vb0, acc[1][0], 0, 0, 0);
      acc[1][1] = __builtin_amdgcn_mfma_f32_16x16x32_bf16(pa1, vb1, acc[1][1], 0, 0, 0);
      acc[1][2] = __builtin_amdgcn_mfma_f32_16x16x32_bf16(pa1, vb2, acc[1][2], 0, 0, 0);
      acc[1][3] = __builtin_amdgcn_mfma_f32_16x16x32_bf16(pa1, vb3, acc[1][3], 0, 0, 0);
    }

    float* ob = out + ((size_t)(b * T_SZ + qt * 64 + wr * 32)) * D_SZ +
                ds * 128 + dg * 64;
#pragma unroll
    for (int mf = 0; mf < 2; ++mf)
#pragma unroll
      for (int nf = 0; nf < 4; ++nf)
#pragma unroll
        for (int r = 0; r < 4; ++r)
          ob[(size_t)(mf * 16 + l4 * 4 + r) * D_SZ + nf * 16 + l15] =
              acc[mf][nf][r];
  }
}

// ===================== BASE FALLBACK (no ws needed) ===================
__global__ __launch_bounds__(NTH) void hdc_attn_fallback(
    const float* __restrict__ x, const float* __restrict__ bvq,
    const float* __restrict__ bvk, const float* __restrict__ bvv,
    float* __restrict__ out) {
  __shared__ ushort Qs[32][1032];
  __shared__ ushort Ks[64][72];
  __shared__ ushort Ps[32][72];
  const int tid = threadIdx.x;
  const int lane = tid & 63;
  const int w = tid >> 6;
  const int rg = w >> 2, cg = w & 3;
  const int l15 = lane & 15, l4 = lane >> 4;
  const int b = blockIdx.x >> 6;
  const int ti = blockIdx.x & 63;
  const int t0 = ti * 32;
  {
    const float4* xr = (const float4*)(x + ((size_t)b * T_SZ + t0) * D_SZ);
    const float4* bq4 = (const float4*)bvq;
#pragma unroll
    for (int i = 0; i < 16; ++i) {
      int flat4 = tid + i * NTH;
      int row = flat4 >> 8, c4 = flat4 & 255;
      float4 v = xr[row * 256 + c4];
      float4 q = bq4[c4];
      uint32_t q0 = sbf(__float_as_uint(v.x), __float_as_uint(q.x));
      uint32_t q1 = sbf(__float_as_uint(v.y), __float_as_uint(q.y));
      uint32_t q2 = sbf(__float_as_uint(v.z), __float_as_uint(q.z));
      uint32_t q3 = sbf(__float_as_uint(v.w), __float_as_uint(q.w));
      *(uint2*)&Qs[row][c4 * 4] = make_uint2(q0 | (q1 << 16), q2 | (q3 << 16));
    }
  }
  uint32_t vsign[16];
#pragma unroll
  for (int f = 0; f < 16; ++f)
    vsign[f] = __float_as_uint(bvv[cg * 256 + f * 16 + l15]) & 0x80000000u;
  f32x4 acc[16];
#pragma unroll
  for (int f = 0; f < 16; ++f) acc[f] = (f32x4){0.f, 0.f, 0.f, 0.f};
  const int nt = (t0 + 32 + 63) / 64;
  for (int st = 0; st < nt; ++st) {
    const int s0 = st * 64;
    f32x4 sacc = (f32x4){0.f, 0.f, 0.f, 0.f};
    for (int dc = 0; dc < D_SZ / 64; ++dc) {
      __syncthreads();
      {
        const int s = tid >> 3;
        const int c8 = (tid & 7) * 8;
        const float* xk = x + ((size_t)b * T_SZ + s0 + s) * D_SZ + dc * 64 + c8;
        const float* bk = bvk + dc * 64 + c8;
        float4 v0 = *(const float4*)xk;
        float4 v1 = *(const float4*)(xk + 4);
        float4 k0 = *(const float4*)bk;
        float4 k1 = *(const float4*)(bk + 4);
        uint32_t w0 = sbf(__float_as_uint(v0.x), __float_as_uint(k0.x)) |
                      (sbf(__float_as_uint(v0.y), __float_as_uint(k0.y)) << 16);
        uint32_t w1 = sbf(__float_as_uint(v0.z), __float_as_uint(k0.z)) |
                      (sbf(__float_as_uint(v0.w), __float_as_uint(k0.w)) << 16);
        uint32_t w2 = sbf(__float_as_uint(v1.x), __float_as_uint(k1.x)) |
                      (sbf(__float_as_uint(v1.y), __float_as_uint(k1.y)) << 16);
        uint32_t w3 = sbf(__float_as_uint(v1.z), __float_as_uint(k1.z)) |
                      (sbf(__float_as_uint(v1.w), __float_as_uint(k1.w)) << 16);
        *(uint4*)&Ks[s][c8] = make_uint4(w0, w1, w2, w3);
      }
      __syncthreads();
#pragma unroll
      for (int h = 0; h < 2; ++h) {
        bf16x8 a = *(const bf16x8*)&Qs[rg * 16 + l15][dc * 64 + h * 32 + l4 * 8];
        bf16x8 kb = *(const bf16x8*)&Ks[cg * 16 + l15][h * 32 + l4 * 8];
        sacc = __builtin_amdgcn_mfma_f32_16x16x32_bf16(a, kb, sacc, 0, 0, 0);
      }
    }
    {
      const int scol = cg * 16 + l15;
      const int sg = s0 + scol;
#pragma unroll
      for (int r = 0; r < 4; ++r) {
        const int m = rg * 16 + l4 * 4 + r;
        float p = 0.f;
        if (sg <= t0 + m) p = 1.f / (1.f + __expf(-0.125f * sacc[r]));
        Ps[m][scol] = (ushort)(__float_as_uint(p) >> 16);
      }
    }
    __syncthreads();
    const float* xv = x + ((size_t)b * T_SZ + s0) * D_SZ;
#pragma unroll
    for (int kk = 0; kk < 2; ++kk) {
      bf16x8 pa = *(const bf16x8*)&Ps[rg * 16 + l15][kk * 32 + l4 * 8];
      const float* xvs = xv + (size_t)(kk * 32 + l4 * 8) * D_SZ;
#pragma unroll
      for (int f = 0; f < 16; ++f) {
        const int n = cg * 256 + f * 16 + l15;
        const float* xn = xvs + n;
        bf16x8 vb;
#pragma unroll
        for (int i = 0; i < 8; ++i) {
          uint32_t u = __float_as_uint(xn[(size_t)i * D_SZ]) ^ vsign[f];
          vb[i] = (short)(u >> 16);
        }
        acc[f] = __builtin_amdgcn_mfma_f32_16x16x32_bf16(pa, vb, acc[f], 0, 0, 0);
      }
    }
  }
  float* orow = out + ((size_t)b * T_SZ + t0) * D_SZ;
#pragma unroll
  for (int f = 0; f < 16; ++f) {
    const int n = cg * 256 + f * 16 + l15;
#pragma unroll
    for (int r = 0; r < 4; ++r) {
      const int m = rg * 16 + l4 * 4 + r;
      orow[(size_t)m * D_SZ + n] = acc[f][r];
    }
  }
}

extern "C" void kernel_launch(void* const* d_in, const int* in_sizes, int n_in,
                              void* d_out, int out_size, void* d_ws, size_t ws_size,
                              hipStream_t stream) {
  const float* x = (const float*)d_in[0];
  const float* bvq = (const float*)d_in[1];
  const float* bvk = (const float*)d_in[2];
  const float* bvv = (const float*)d_in[3];
  float* out = (float*)d_out;

  const size_t QB_SZ = (size_t)B_SZ * T_SZ * D_SZ;     // 8 MB (i8)
  const size_t VT_SZ = QB_SZ * 2;                      // 16 MB (bf16)
  const size_t P_SZ = (size_t)B_SZ * T_SZ * T_SZ * 2;  // 32 MB (bf16)
  const size_t NEED_FULL = QB_SZ * 2 + VT_SZ + P_SZ;   // 64 MB

  if (ws_size >= NEED_FULL) {
    char* Qb = (char*)d_ws;
    char* Kb = Qb + QB_SZ;
    ushort* Vt2 = (ushort*)(Kb + QB_SZ);
    ushort* P2 = (ushort*)((char*)Vt2 + VT_SZ);
    hipLaunchKernelGGL(prep_kernel, dim3(B_SZ * 32 * 16), dim3(256), 0, stream,
                       x, bvq, bvk, bvv, Qb, Kb, Vt2);
    hipLaunchKernelGGL(score_kernel, dim3(544), dim3(NTH), 0, stream,
                       Qb, Kb, P2);
    hipLaunchKernelGGL(pv_kernel, dim3(512), dim3(256), 0, stream,
                       P2, Vt2, out);
  } else {
    hipLaunchKernelGGL(hdc_attn_fallback, dim3(B_SZ * 64), dim3(NTH), 0, stream,
                       x, bvq, bvk, bvv, out);
  }
}

// Round 15
// 69.638 us; speedup vs baseline: 1.2340x; 1.0343x over previous
//
#include <hip/hip_runtime.h>
#include <hip/hip_bf16.h>
#include <stdint.h>
#include <math.h>

#define B_SZ 4
#define T_SZ 2048
#define D_SZ 1024

constexpr int NTH = 512;

typedef short bf16x8 __attribute__((ext_vector_type(8)));
typedef float f32x4 __attribute__((ext_vector_type(4)));
typedef int i32x4 __attribute__((ext_vector_type(4)));
typedef unsigned short ushort8 __attribute__((ext_vector_type(8)));

__device__ __forceinline__ uint32_t sbf(uint32_t xu, uint32_t su) {
  return 0x3F80u | (((xu ^ su) >> 16) & 0x8000u);
}

__device__ __forceinline__ ushort f2bf(float f) {  // RNE f32->bf16
  uint32_t u = __float_as_uint(f);
  return (ushort)((u + 0x7FFFu + ((u >> 16) & 1u)) >> 16);
}

// async 16B global->LDS (dest = wave-uniform base + lane*16 pattern)
__device__ __forceinline__ void glds16(const void* g, void* l) {
  __builtin_amdgcn_global_load_lds(
      (const __attribute__((address_space(1))) void*)g,
      (__attribute__((address_space(3))) void*)l, 16, 0, 0);
}

// Fragment-major layouts (bf16):
//   P2[b][q4=q/16][s8=s/8][q&15][s&7]   : q4-stride 256*128, s8-stride 128
//   Vt2[b][d4=d/16][s8][d&15][s&7]
// MFMA operand load: lane(l15,l4) reads 16B -> one contiguous 1KB per wave.

// ============================ PREP KERNEL =============================
// (R11-proven, verbatim) Qb,Kb: int8 signs in [B][T][D].  Vt2: bf16
// x*sign(bv), fragment-major.
__global__ __launch_bounds__(256) void prep_kernel(
    const float* __restrict__ x, const float* __restrict__ bvq,
    const float* __restrict__ bvk, const float* __restrict__ bvv,
    char* __restrict__ Qb, char* __restrict__ Kb, ushort* __restrict__ Vt2) {
  __shared__ ushort vt[64][72];
  const int bid = blockIdx.x;
  const int dt = bid & 15;
  const int tt = (bid >> 4) & 31;
  const int b = bid >> 9;
  const int t0 = tt * 64, d0 = dt * 64;
  const int tid = threadIdx.x;

#pragma unroll
  for (int p = 0; p < 4; ++p) {
    const int row = p * 16 + (tid >> 4);
    const int c4 = tid & 15;
    const size_t idx = ((size_t)(b * T_SZ + t0 + row)) * D_SZ + d0 + c4 * 4;
    float4 v = *(const float4*)(x + idx);
    float4 q = *(const float4*)(bvq + d0 + c4 * 4);
    float4 k = *(const float4*)(bvk + d0 + c4 * 4);
    float4 s = *(const float4*)(bvv + d0 + c4 * 4);
    uint32_t xu[4] = {__float_as_uint(v.x), __float_as_uint(v.y),
                      __float_as_uint(v.z), __float_as_uint(v.w)};
    uint32_t qu[4] = {__float_as_uint(q.x), __float_as_uint(q.y),
                      __float_as_uint(q.z), __float_as_uint(q.w)};
    uint32_t ku[4] = {__float_as_uint(k.x), __float_as_uint(k.y),
                      __float_as_uint(k.z), __float_as_uint(k.w)};
    uint32_t su[4] = {__float_as_uint(s.x), __float_as_uint(s.y),
                      __float_as_uint(s.z), __float_as_uint(s.w)};
    uint32_t qw = 0, kw = 0;
#pragma unroll
    for (int j = 0; j < 4; ++j) {
      uint32_t qb = ((xu[j] ^ qu[j]) & 0x80000000u) ? 0xFFu : 0x01u;
      uint32_t kb = ((xu[j] ^ ku[j]) & 0x80000000u) ? 0xFFu : 0x01u;
      qw |= qb << (8 * j);
      kw |= kb << (8 * j);
      vt[row][c4 * 4 + j] = f2bf(__uint_as_float(xu[j] ^ (su[j] & 0x80000000u)));
    }
    *(uint32_t*)(Qb + idx) = qw;
    *(uint32_t*)(Kb + idx) = kw;
  }
  __syncthreads();
#pragma unroll
  for (int p = 0; p < 2; ++p) {
    const int dr = p * 32 + (tid >> 3);
    const int tc = tid & 7;
    ushort8 o;
#pragma unroll
    for (int j = 0; j < 8; ++j) o[j] = vt[tc * 8 + j][dr];
    const int dglob = d0 + dr;
    const int s8 = (t0 >> 3) + tc;
    *(ushort8*)(Vt2 +
                (((size_t)(b * 64 + (dglob >> 4))) * 256 + s8) * 128 +
                (dglob & 15) * 8) = o;
  }
}

// ============================ SCORE KERNEL ============================
// (R11-proven body) 128x128 tile per block, 8 waves (wave = 32q x 64s),
// BK=128, LDS double-buffered; order: vmcnt(0) -> barrier -> STAGE(next).
// LPT launch order: triangular index reversed (big qt first) to kill the
// tail at ~2.1 blocks/CU. Final store -> fragment-major P2.
__global__ __launch_bounds__(NTH) void score_kernel(
    const char* __restrict__ Qb, const char* __restrict__ Kb,
    ushort* __restrict__ P2) {
  __shared__ __align__(16) unsigned char Qs[2][128 * 128];  // 32 KB
  __shared__ __align__(16) unsigned char Ks[2][128 * 128];  // 32 KB

  const int bid = blockIdx.x;
  const int xcd = bid & 7;
  const int b = xcd >> 1;
  const int j = 135 - (((bid >> 3) << 1) + (xcd & 1));  // big tiles first
  int qt = (int)((sqrtf(8.f * (float)j + 1.f) - 1.f) * 0.5f);
  while ((qt + 1) * (qt + 2) / 2 <= j) ++qt;
  while (qt * (qt + 1) / 2 > j) --qt;
  const int st = j - qt * (qt + 1) / 2;

  const int tid = threadIdx.x;
  const int lane = tid & 63, w = tid >> 6;
  const int wr = w >> 1, wc = w & 1;
  const int l15 = lane & 15, l4 = lane >> 4;

  const size_t qrow0 = ((size_t)(b * T_SZ + qt * 128)) * D_SZ;
  const size_t krow0 = ((size_t)(b * T_SZ + st * 128)) * D_SZ;

  i32x4 sacc[2][4];
#pragma unroll
  for (int mf = 0; mf < 2; ++mf)
#pragma unroll
    for (int nf = 0; nf < 4; ++nf) sacc[mf][nf] = (i32x4){0, 0, 0, 0};

  auto STAGE = [&](int buf, int ks) {
#pragma unroll
    for (int i = 0; i < 4; ++i) {
      const int isK = i >> 1;
      const int fi = tid + (i & 1) * 512;
      const int row = fi >> 3, c = fi & 7;
      const int cs = c ^ (row & 7);
      const char* src = (isK ? Kb + krow0 : Qb + qrow0) +
                        (size_t)row * D_SZ + ks * 128 + cs * 16;
      unsigned char* dst = (isK ? Ks[buf] : Qs[buf]) + fi * 16;
      glds16(src, dst);
    }
  };

  STAGE(0, 0);
  for (int ks = 0; ks < 8; ++ks) {
    asm volatile("s_waitcnt vmcnt(0)" ::: "memory");
    __builtin_amdgcn_s_barrier();
    if (ks + 1 < 8) STAGE((ks + 1) & 1, ks + 1);
    const int buf = ks & 1;
#pragma unroll
    for (int kc = 0; kc < 2; ++kc) {
      i32x4 af[2], bfr[4];
#pragma unroll
      for (int mf = 0; mf < 2; ++mf) {
        const int row = wr * 32 + mf * 16 + l15;
        const int ch = (kc * 4 + l4) ^ (row & 7);
        af[mf] = *(const i32x4*)(Qs[buf] + row * 128 + ch * 16);
      }
#pragma unroll
      for (int nf = 0; nf < 4; ++nf) {
        const int row = wc * 64 + nf * 16 + l15;
        const int ch = (kc * 4 + l4) ^ (row & 7);
        bfr[nf] = *(const i32x4*)(Ks[buf] + row * 128 + ch * 16);
      }
#pragma unroll
      for (int mf = 0; mf < 2; ++mf)
#pragma unroll
        for (int nf = 0; nf < 4; ++nf)
          sacc[mf][nf] = __builtin_amdgcn_mfma_i32_16x16x64_i8(
              af[mf], bfr[nf], sacc[mf][nf], 0, 0, 0);
    }
    asm volatile("s_waitcnt lgkmcnt(0)" ::: "memory");
  }

  // sigmoid + causal mask + fragment-major write
#pragma unroll
  for (int mf = 0; mf < 2; ++mf)
#pragma unroll
    for (int nf = 0; nf < 4; ++nf)
#pragma unroll
      for (int r = 0; r < 4; ++r) {
        const int qg = qt * 128 + wr * 32 + mf * 16 + l4 * 4 + r;
        const int sg = st * 128 + wc * 64 + nf * 16 + l15;
        float p = 1.f / (1.f + __expf(-0.125f * (float)sacc[mf][nf][r]));
        if (sg > qg) p = 0.f;
        P2[(((size_t)(b * 128 + (qg >> 4))) * 256 + (sg >> 3)) * 128 +
           (qg & 15) * 8 + (sg & 7)] = f2bf(p);
      }
}

// ============================== PV KERNEL =============================
// (R11-proven; unroll 2->4 for deeper MLP) out = P*V, pure register GEMM,
// no LDS/barriers. Block = 64q x 128d, 4 waves. Pair (pr,31-pr): 33 s-tiles
// per block. xcd = 2b + (pr&1): all 8 ds-blocks of one (b,qt) on ONE XCD.
__global__ __launch_bounds__(256) void pv_kernel(
    const ushort* __restrict__ P2, const ushort* __restrict__ Vt2,
    float* __restrict__ out) {
  const int bid = blockIdx.x;
  const int xcd = bid & 7;
  const int idx = bid >> 3;            // 0..63
  const int ds = idx & 7;              // 128-col d-slice
  const int prh = idx >> 3;            // 0..7
  const int pr = prh * 2 + (xcd & 1);  // 0..15, parity matches xcd
  const int b = xcd >> 1;

  const int tid = threadIdx.x;
  const int lane = tid & 63, w = tid >> 6;
  const int wr = w >> 1, dg = w & 1;
  const int l15 = lane & 15, l4 = lane >> 4;

  const size_t d4base = (size_t)b * 64 + ds * 8 + dg * 4;

  for (int half = 0; half < 2; ++half) {
    const int qt = half ? (31 - pr) : pr;

    f32x4 acc[2][4];
#pragma unroll
    for (int mf = 0; mf < 2; ++mf)
#pragma unroll
      for (int nf = 0; nf < 4; ++nf) acc[mf][nf] = (f32x4){0.f, 0.f, 0.f, 0.f};

    const size_t q4base = (size_t)b * 128 + qt * 4 + wr * 2;

    const ushort* pP0 = P2 + ((q4base + 0) * 256 + l4) * 128 + l15 * 8;
    const ushort* pP1 = P2 + ((q4base + 1) * 256 + l4) * 128 + l15 * 8;
    const ushort* pV0 = Vt2 + ((d4base + 0) * 256 + l4) * 128 + l15 * 8;
    const ushort* pV1 = Vt2 + ((d4base + 1) * 256 + l4) * 128 + l15 * 8;
    const ushort* pV2 = Vt2 + ((d4base + 2) * 256 + l4) * 128 + l15 * 8;
    const ushort* pV3 = Vt2 + ((d4base + 3) * 256 + l4) * 128 + l15 * 8;

    const int nk = (qt + 1) * 2;  // k-steps of 32 s each
#pragma unroll 4
    for (int k = 0; k < nk; ++k) {
      bf16x8 pa0 = *(const bf16x8*)pP0;
      bf16x8 pa1 = *(const bf16x8*)pP1;
      bf16x8 vb0 = *(const bf16x8*)pV0;
      bf16x8 vb1 = *(const bf16x8*)pV1;
      bf16x8 vb2 = *(const bf16x8*)pV2;
      bf16x8 vb3 = *(const bf16x8*)pV3;
      pP0 += 512; pP1 += 512;
      pV0 += 512; pV1 += 512; pV2 += 512; pV3 += 512;
      acc[0][0] = __builtin_amdgcn_mfma_f32_16x16x32_bf16(pa0, vb0, acc[0][0], 0, 0, 0);
      acc[0][1] = __builtin_amdgcn_mfma_f32_16x16x32_bf16(pa0, vb1, acc[0][1], 0, 0, 0);
      acc[0][2] = __builtin_amdgcn_mfma_f32_16x16x32_bf16(pa0, vb2, acc[0][2], 0, 0, 0);
      acc[0][3] = __builtin_amdgcn_mfma_f32_16x16x32_bf16(pa0, vb3, acc[0][3], 0, 0, 0);
      acc[1][0] = __builtin_amdgcn_mfma_f32_16x16x32_bf16(pa1, vb0, acc[1][0], 0, 0, 0);
      acc[1][1] = __builtin_amdgcn_mfma_f32_16x16x32_bf16(pa1, vb1, acc[1][1], 0, 0, 0);
      acc[1][2] = __builtin_amdgcn_mfma_f32_16x16x32_bf16(pa1, vb2, acc[1][2], 0, 0, 0);
      acc[1][3] = __builtin_amdgcn_mfma_f32_16x16x32_bf16(pa1, vb3, acc[1][3], 0, 0, 0);
    }

    float* ob = out + ((size_t)(b * T_SZ + qt * 64 + wr * 32)) * D_SZ +
                ds * 128 + dg * 64;
#pragma unroll
    for (int mf = 0; mf < 2; ++mf)
#pragma unroll
      for (int nf = 0; nf < 4; ++nf)
#pragma unroll
        for (int r = 0; r < 4; ++r)
          ob[(size_t)(mf * 16 + l4 * 4 + r) * D_SZ + nf * 16 + l15] =
              acc[mf][nf][r];
  }
}

// ===================== BASE FALLBACK (no ws needed) ===================
__global__ __launch_bounds__(NTH) void hdc_attn_fallback(
    const float* __restrict__ x, const float* __restrict__ bvq,
    const float* __restrict__ bvk, const float* __restrict__ bvv,
    float* __restrict__ out) {
  __shared__ ushort Qs[32][1032];
  __shared__ ushort Ks[64][72];
  __shared__ ushort Ps[32][72];
  const int tid = threadIdx.x;
  const int lane = tid & 63;
  const int w = tid >> 6;
  const int rg = w >> 2, cg = w & 3;
  const int l15 = lane & 15, l4 = lane >> 4;
  const int b = blockIdx.x >> 6;
  const int ti = blockIdx.x & 63;
  const int t0 = ti * 32;
  {
    const float4* xr = (const float4*)(x + ((size_t)b * T_SZ + t0) * D_SZ);
    const float4* bq4 = (const float4*)bvq;
#pragma unroll
    for (int i = 0; i < 16; ++i) {
      int flat4 = tid + i * NTH;
      int row = flat4 >> 8, c4 = flat4 & 255;
      float4 v = xr[row * 256 + c4];
      float4 q = bq4[c4];
      uint32_t q0 = sbf(__float_as_uint(v.x), __float_as_uint(q.x));
      uint32_t q1 = sbf(__float_as_uint(v.y), __float_as_uint(q.y));
      uint32_t q2 = sbf(__float_as_uint(v.z), __float_as_uint(q.z));
      uint32_t q3 = sbf(__float_as_uint(v.w), __float_as_uint(q.w));
      *(uint2*)&Qs[row][c4 * 4] = make_uint2(q0 | (q1 << 16), q2 | (q3 << 16));
    }
  }
  uint32_t vsign[16];
#pragma unroll
  for (int f = 0; f < 16; ++f)
    vsign[f] = __float_as_uint(bvv[cg * 256 + f * 16 + l15]) & 0x80000000u;
  f32x4 acc[16];
#pragma unroll
  for (int f = 0; f < 16; ++f) acc[f] = (f32x4){0.f, 0.f, 0.f, 0.f};
  const int nt = (t0 + 32 + 63) / 64;
  for (int st = 0; st < nt; ++st) {
    const int s0 = st * 64;
    f32x4 sacc = (f32x4){0.f, 0.f, 0.f, 0.f};
    for (int dc = 0; dc < D_SZ / 64; ++dc) {
      __syncthreads();
      {
        const int s = tid >> 3;
        const int c8 = (tid & 7) * 8;
        const float* xk = x + ((size_t)b * T_SZ + s0 + s) * D_SZ + dc * 64 + c8;
        const float* bk = bvk + dc * 64 + c8;
        float4 v0 = *(const float4*)xk;
        float4 v1 = *(const float4*)(xk + 4);
        float4 k0 = *(const float4*)bk;
        float4 k1 = *(const float4*)(bk + 4);
        uint32_t w0 = sbf(__float_as_uint(v0.x), __float_as_uint(k0.x)) |
                      (sbf(__float_as_uint(v0.y), __float_as_uint(k0.y)) << 16);
        uint32_t w1 = sbf(__float_as_uint(v0.z), __float_as_uint(k0.z)) |
                      (sbf(__float_as_uint(v0.w), __float_as_uint(k0.w)) << 16);
        uint32_t w2 = sbf(__float_as_uint(v1.x), __float_as_uint(k1.x)) |
                      (sbf(__float_as_uint(v1.y), __float_as_uint(k1.y)) << 16);
        uint32_t w3 = sbf(__float_as_uint(v1.z), __float_as_uint(k1.z)) |
                      (sbf(__float_as_uint(v1.w), __float_as_uint(k1.w)) << 16);
        *(uint4*)&Ks[s][c8] = make_uint4(w0, w1, w2, w3);
      }
      __syncthreads();
#pragma unroll
      for (int h = 0; h < 2; ++h) {
        bf16x8 a = *(const bf16x8*)&Qs[rg * 16 + l15][dc * 64 + h * 32 + l4 * 8];
        bf16x8 kb = *(const bf16x8*)&Ks[cg * 16 + l15][h * 32 + l4 * 8];
        sacc = __builtin_amdgcn_mfma_f32_16x16x32_bf16(a, kb, sacc, 0, 0, 0);
      }
    }
    {
      const int scol = cg * 16 + l15;
      const int sg = s0 + scol;
#pragma unroll
      for (int r = 0; r < 4; ++r) {
        const int m = rg * 16 + l4 * 4 + r;
        float p = 0.f;
        if (sg <= t0 + m) p = 1.f / (1.f + __expf(-0.125f * sacc[r]));
        Ps[m][scol] = (ushort)(__float_as_uint(p) >> 16);
      }
    }
    __syncthreads();
    const float* xv = x + ((size_t)b * T_SZ + s0) * D_SZ;
#pragma unroll
    for (int kk = 0; kk < 2; ++kk) {
      bf16x8 pa = *(const bf16x8*)&Ps[rg * 16 + l15][kk * 32 + l4 * 8];
      const float* xvs = xv + (size_t)(kk * 32 + l4 * 8) * D_SZ;
#pragma unroll
      for (int f = 0; f < 16; ++f) {
        const int n = cg * 256 + f * 16 + l15;
        const float* xn = xvs + n;
        bf16x8 vb;
#pragma unroll
        for (int i = 0; i < 8; ++i) {
          uint32_t u = __float_as_uint(xn[(size_t)i * D_SZ]) ^ vsign[f];
          vb[i] = (short)(u >> 16);
        }
        acc[f] = __builtin_amdgcn_mfma_f32_16x16x32_bf16(pa, vb, acc[f], 0, 0, 0);
      }
    }
  }
  float* orow = out + ((size_t)b * T_SZ + t0) * D_SZ;
#pragma unroll
  for (int f = 0; f < 16; ++f) {
    const int n = cg * 256 + f * 16 + l15;
#pragma unroll
    for (int r = 0; r < 4; ++r) {
      const int m = rg * 16 + l4 * 4 + r;
      orow[(size_t)m * D_SZ + n] = acc[f][r];
    }
  }
}

extern "C" void kernel_launch(void* const* d_in, const int* in_sizes, int n_in,
                              void* d_out, int out_size, void* d_ws, size_t ws_size,
                              hipStream_t stream) {
  const float* x = (const float*)d_in[0];
  const float* bvq = (const float*)d_in[1];
  const float* bvk = (const float*)d_in[2];
  const float* bvv = (const float*)d_in[3];
  float* out = (float*)d_out;

  const size_t QB_SZ = (size_t)B_SZ * T_SZ * D_SZ;     // 8 MB (i8)
  const size_t VT_SZ = QB_SZ * 2;                      // 16 MB (bf16)
  const size_t P_SZ = (size_t)B_SZ * T_SZ * T_SZ * 2;  // 32 MB (bf16)
  const size_t NEED_FULL = QB_SZ * 2 + VT_SZ + P_SZ;   // 64 MB

  if (ws_size >= NEED_FULL) {
    char* Qb = (char*)d_ws;
    char* Kb = Qb + QB_SZ;
    ushort* Vt2 = (ushort*)(Kb + QB_SZ);
    ushort* P2 = (ushort*)((char*)Vt2 + VT_SZ);
    hipLaunchKernelGGL(prep_kernel, dim3(B_SZ * 32 * 16), dim3(256), 0, stream,
                       x, bvq, bvk, bvv, Qb, Kb, Vt2);
    hipLaunchKernelGGL(score_kernel, dim3(544), dim3(NTH), 0, stream,
                       Qb, Kb, P2);
    hipLaunchKernelGGL(pv_kernel, dim3(512), dim3(256), 0, stream,
                       P2, Vt2, out);
  } else {
    hipLaunchKernelGGL(hdc_attn_fallback, dim3(B_SZ * 64), dim3(NTH), 0, stream,
                       x, bvq, bvk, bvv, out);
  }
}